// Round 1
// baseline (9145.216 us; speedup 1.0000x reference)
//
#include <hip/hip_runtime.h>
#include <cstdint>
#include <cstddef>

// ---------------------------------------------------------------------------
// GIN (GINEConv x3) forward, f32.
//   h = x@W_enc + b_enc
//   per layer: m_e = relu(h[src]+ (edge_attr@W_ee+b_ee)) * atten
//              z = (1+eps)*h + scatter_add(m, dst)
//              h = relu( relu(BN(z@W1+b1)) @ W2 + b2 )
// ---------------------------------------------------------------------------

// C = act(A @ W + bias); A:[n,128], W:[128,128] row-major, 32-row tiles.
// MODE 0: none (encoder), 1: BN+ReLU (mlp1), 2: ReLU (mlp2)
template <int MODE>
__global__ __launch_bounds__(256, 2) void gemm128(
    const float* __restrict__ A, const float* __restrict__ W,
    const float* __restrict__ bias, float* __restrict__ C, int n,
    const float* __restrict__ g, const float* __restrict__ bta,
    const float* __restrict__ mu, const float* __restrict__ var)
{
    __shared__ float Wt[128][128];   // 64 KB
    __shared__ float At[32][128];    // 16 KB
    const int t = threadIdx.x;

    // stage W (128x128 f32 = 4096 float4)
    const float4* W4 = (const float4*)W;
    float4* Wt4 = (float4*)&Wt[0][0];
#pragma unroll
    for (int i = 0; i < 16; ++i) Wt4[t + 256 * i] = W4[t + 256 * i];

    const int row0 = blockIdx.x * 32;
    const int nrows = min(32, n - row0);
    const float4* A4 = (const float4*)(A + (size_t)row0 * 128);
    float4* At4 = (float4*)&At[0][0];
#pragma unroll
    for (int i = 0; i < 4; ++i) {
        int idx = t + 256 * i;
        if (idx < nrows * 32) At4[idx] = A4[idx];
    }
    __syncthreads();

    const int tx = t & 31, ty = t >> 5;   // tx: col-group (4 cols), ty: row-group (4 rows)
    float acc[4][4] = {};
#pragma unroll
    for (int k = 0; k < 128; k += 4) {
        float4 w4[4];
#pragma unroll
        for (int kk = 0; kk < 4; ++kk) w4[kk] = *(const float4*)&Wt[k + kk][tx * 4];
#pragma unroll
        for (int r = 0; r < 4; ++r) {
            float4 a = *(const float4*)&At[ty * 4 + r][k];
            float ar[4] = {a.x, a.y, a.z, a.w};
#pragma unroll
            for (int kk = 0; kk < 4; ++kk) {
                acc[r][0] = fmaf(ar[kk], w4[kk].x, acc[r][0]);
                acc[r][1] = fmaf(ar[kk], w4[kk].y, acc[r][1]);
                acc[r][2] = fmaf(ar[kk], w4[kk].z, acc[r][2]);
                acc[r][3] = fmaf(ar[kk], w4[kk].w, acc[r][3]);
            }
        }
    }

    const int c0 = tx * 4;
    float bv[4], sc[4], sh[4];
#pragma unroll
    for (int c = 0; c < 4; ++c) bv[c] = bias[c0 + c];
    if constexpr (MODE == 1) {
#pragma unroll
        for (int c = 0; c < 4; ++c) {
            float s = g[c0 + c] * rsqrtf(var[c0 + c] + 1e-5f);
            sc[c] = s;
            sh[c] = bta[c0 + c] - mu[c0 + c] * s;
        }
    }
#pragma unroll
    for (int r = 0; r < 4; ++r) {
        int row = row0 + ty * 4 + r;
        if (row < n) {
            float4 o;
            float* op = &o.x;
#pragma unroll
            for (int c = 0; c < 4; ++c) {
                float v = acc[r][c] + bv[c];
                if constexpr (MODE == 1) { v = fmaf(v, sc[c], sh[c]); v = fmaxf(v, 0.f); }
                if constexpr (MODE == 2) { v = fmaxf(v, 0.f); }
                op[c] = v;
            }
            *(float4*)&C[(size_t)row * 128 + c0] = o;
        }
    }
}

// zbuf = (1+eps[layer]) * h
__global__ void scale_init(const float* __restrict__ h, float* __restrict__ z,
                           const float* __restrict__ eps, int layer, int n4)
{
    const float s = 1.0f + eps[layer];
    int i = blockIdx.x * blockDim.x + threadIdx.x;
    const int stride = gridDim.x * blockDim.x;
    const float4* h4 = (const float4*)h;
    float4* z4 = (float4*)z;
    for (; i < n4; i += stride) {
        float4 v = h4[i];
        v.x *= s; v.y *= s; v.z *= s; v.w *= s;
        z4[i] = v;
    }
}

// one wave per edge (grid-stride): m = relu(h[src] + edge_attr@W_ee + b_ee) * atten
// atomically accumulated into zbuf[dst].
__global__ __launch_bounds__(256) void edge_kernel(
    const float* __restrict__ h, const int* __restrict__ ei,
    const float* __restrict__ eattr, const float* __restrict__ eatten,
    const float* __restrict__ W_ee, const float* __restrict__ b_ee,
    float* __restrict__ zbuf, int E)
{
    __shared__ float Wee[16][128];   // 8 KB
    __shared__ float bee[128];
    const int t = threadIdx.x;
    const float4* We4 = (const float4*)W_ee;
    float4* Ws4 = (float4*)&Wee[0][0];
#pragma unroll
    for (int i = 0; i < 2; ++i) Ws4[t + 256 * i] = We4[t + 256 * i];
    if (t < 128) bee[t] = b_ee[t];
    __syncthreads();

    const int lane = t & 63;
    const int c = lane * 2;                      // this lane's 2 columns
    const long wid = (long)blockIdx.x * 4 + (t >> 6);
    const long nw = (long)gridDim.x * 4;
    for (long e = wid; e < E; e += nw) {
        const int src = ei[e];
        const int dst = ei[E + e];
        const float att = eatten[e];
        union { float4 v[4]; float f[16]; } ea;
        const float4* eap = (const float4*)(eattr + e * 16);
        ea.v[0] = eap[0]; ea.v[1] = eap[1]; ea.v[2] = eap[2]; ea.v[3] = eap[3];
        float2 hv = *(const float2*)&h[(size_t)src * 128 + c];
        float e0 = bee[c], e1 = bee[c + 1];
#pragma unroll
        for (int k = 0; k < 16; ++k) {
            float2 w = *(const float2*)&Wee[k][c];
            e0 = fmaf(ea.f[k], w.x, e0);
            e1 = fmaf(ea.f[k], w.y, e1);
        }
        float m0 = fmaxf(hv.x + e0, 0.f) * att;
        float m1 = fmaxf(hv.y + e1, 0.f) * att;
        float* zp = &zbuf[(size_t)dst * 128 + c];
        unsafeAtomicAdd(zp, m0);
        unsafeAtomicAdd(zp + 1, m1);
    }
}

extern "C" void kernel_launch(void* const* d_in, const int* in_sizes, int n_in,
                              void* d_out, int out_size, void* d_ws, size_t ws_size,
                              hipStream_t stream)
{
    const float* x      = (const float*)d_in[0];
    const int*   ei     = (const int*)d_in[1];
    // d_in[2] = batch (unused by reference)
    const float* eattr  = (const float*)d_in[3];
    const float* eatten = (const float*)d_in[4];
    const float* W_enc  = (const float*)d_in[5];
    const float* b_enc  = (const float*)d_in[6];
    const float* W_ee   = (const float*)d_in[7];
    const float* b_ee   = (const float*)d_in[8];
    const float* eps    = (const float*)d_in[9];
    const float* W1     = (const float*)d_in[10];
    const float* b1     = (const float*)d_in[11];
    const float* gam    = (const float*)d_in[12];
    const float* bet    = (const float*)d_in[13];
    const float* mu     = (const float*)d_in[14];
    const float* var    = (const float*)d_in[15];
    const float* W2     = (const float*)d_in[16];
    const float* b2     = (const float*)d_in[17];

    const int N = in_sizes[0] / 128;
    const int E = in_sizes[1] / 2;
    const int L = in_sizes[9];

    float* h    = (float*)d_out;   // [N,128]
    float* zbuf = (float*)d_ws;    // [N,128] scratch (25.6 MB)

    const int tiles = (N + 31) / 32;

    // encoder: h = x @ W_enc + b_enc
    gemm128<0><<<tiles, 256, 0, stream>>>(x, W_enc, b_enc, h, N,
                                          nullptr, nullptr, nullptr, nullptr);

    const int n4 = N * 128 / 4;
    for (int i = 0; i < L; ++i) {
        scale_init<<<2048, 256, 0, stream>>>(h, zbuf, eps, i, n4);
        edge_kernel<<<2048, 256, 0, stream>>>(h, ei, eattr, eatten, W_ee, b_ee, zbuf, E);
        // z1 = relu(BN(zbuf@W1+b1)) -> h (h is dead after edge_kernel)
        gemm128<1><<<tiles, 256, 0, stream>>>(zbuf, W1 + (size_t)i * 128 * 128, b1 + i * 128,
                                              h, N, gam + i * 128, bet + i * 128,
                                              mu + i * 128, var + i * 128);
        // h = relu(z1@W2+b2) (in-place per-tile: block stages its rows before writing)
        gemm128<2><<<tiles, 256, 0, stream>>>(h, W2 + (size_t)i * 128 * 128, b2 + i * 128,
                                              h, N, nullptr, nullptr, nullptr, nullptr);
    }
}

// Round 2
// 2320.860 us; speedup vs baseline: 3.9404x; 3.9404x over previous
//
#include <hip/hip_runtime.h>
#include <cstdint>
#include <cstddef>

// ---------------------------------------------------------------------------
// GIN (GINEConv x3) forward, f32.
//   h  = x@W_enc + b_enc                      (gemm_enc; also writes z0 = (1+eps0)h)
//   per layer i:
//     edge: m_e = relu(h[src] + edge_attr@W_ee + b_ee) * atten, atomically
//           accumulated into z (pre-initialized to (1+eps_i) h)
//     mlp:  h = relu( relu(BN(z@W1+b1)) @ W2 + b2 )   (gemm_mlp, fused;
//           also writes z_{i+1} = (1+eps_{i+1}) h when another layer follows)
// ---------------------------------------------------------------------------

// ---- packed-f32x2 atomic with compile-safe fallback ------------------------
template <class T>
__device__ inline auto add2_impl(T* p, T v, int)
    -> decltype(unsafeAtomicAdd(p, v), void()) {
    unsafeAtomicAdd(p, v);                       // global_atomic_pk_add_f32
}
template <class T>
__device__ inline void add2_impl(T* p, T v, long) {
    unsafeAtomicAdd(&p->x, v.x);
    unsafeAtomicAdd(&p->y, v.y);
}
__device__ inline void atomic_add2(float* p, float x, float y) {
    add2_impl(reinterpret_cast<float2*>(p), make_float2(x, y), 0);
}

// ---------------------------------------------------------------------------
// Encoder GEMM: h = A@W + b ; z = (1+eps[0])*h.  A:[n,128], W:[128,128].
// 512 threads, 64-row tile, W K-streamed via 2x(16x128) LDS double buffer.
// ---------------------------------------------------------------------------
__global__ __launch_bounds__(512, 4) void gemm_enc(
    const float* __restrict__ A, const float* __restrict__ W,
    const float* __restrict__ bias, float* __restrict__ H,
    float* __restrict__ Z, const float* __restrict__ eps, int n)
{
    __shared__ float At[64][128];     // 32 KB
    __shared__ float Wb[2][16][128];  // 16 KB
    const int t = threadIdx.x;
    const int tx = t & 31, ty = t >> 5;

    const int row0 = blockIdx.x * 64;
    const int nrows = min(64, n - row0);
    const int lim = nrows * 32;
    const float4* A4 = (const float4*)(A + (size_t)row0 * 128);
    float4* At4 = (float4*)&At[0][0];
#pragma unroll
    for (int i = 0; i < 4; ++i) {
        int idx = t + 512 * i;
        if (idx < lim) At4[idx] = A4[idx];
    }
    const float4* W4 = (const float4*)W;
    ((float4*)&Wb[0][0][0])[t] = W4[t];
    __syncthreads();

    float acc[4][4] = {};
    for (int c = 0; c < 8; ++c) {
        const int buf = c & 1;
        float4 wnext;
        if (c < 7) wnext = W4[(c + 1) * 512 + t];
#pragma unroll
        for (int g = 0; g < 4; ++g) {
            float4 w4[4];
#pragma unroll
            for (int kk = 0; kk < 4; ++kk) w4[kk] = *(const float4*)&Wb[buf][g * 4 + kk][tx * 4];
#pragma unroll
            for (int r = 0; r < 4; ++r) {
                float4 a = *(const float4*)&At[ty * 4 + r][c * 16 + g * 4];
                float ar[4] = {a.x, a.y, a.z, a.w};
#pragma unroll
                for (int kk = 0; kk < 4; ++kk) {
                    acc[r][0] = fmaf(ar[kk], w4[kk].x, acc[r][0]);
                    acc[r][1] = fmaf(ar[kk], w4[kk].y, acc[r][1]);
                    acc[r][2] = fmaf(ar[kk], w4[kk].z, acc[r][2]);
                    acc[r][3] = fmaf(ar[kk], w4[kk].w, acc[r][3]);
                }
            }
        }
        if (c < 7) ((float4*)&Wb[buf ^ 1][0][0])[t] = wnext;
        __syncthreads();
    }

    const int c0 = tx * 4;
    const float s = 1.0f + eps[0];
    float bv[4];
#pragma unroll
    for (int c = 0; c < 4; ++c) bv[c] = bias[c0 + c];
#pragma unroll
    for (int r = 0; r < 4; ++r) {
        int row = row0 + ty * 4 + r;
        if (row < n) {
            float4 o, z;
            o.x = acc[r][0] + bv[0]; o.y = acc[r][1] + bv[1];
            o.z = acc[r][2] + bv[2]; o.w = acc[r][3] + bv[3];
            z.x = o.x * s; z.y = o.y * s; z.z = o.z * s; z.w = o.w * s;
            *(float4*)&H[(size_t)row * 128 + c0] = o;
            *(float4*)&Z[(size_t)row * 128 + c0] = z;
        }
    }
}

// ---------------------------------------------------------------------------
// Fused MLP: h = relu( relu(BN(Z@W1+b1)) @ W2 + b2 ), optional Znext=(1+eps)h.
// ---------------------------------------------------------------------------
__global__ __launch_bounds__(512, 4) void gemm_mlp(
    const float* __restrict__ Z,
    const float* __restrict__ W1, const float* __restrict__ b1,
    const float* __restrict__ gam, const float* __restrict__ bet,
    const float* __restrict__ mu, const float* __restrict__ var,
    const float* __restrict__ W2, const float* __restrict__ b2,
    float* __restrict__ H, float* __restrict__ Znext,
    const float* __restrict__ eps, int next, int n)
{
    __shared__ float At[64][128];     // 32 KB; holds A, then Y
    __shared__ float Wb[2][16][128];  // 16 KB
    const int t = threadIdx.x;
    const int tx = t & 31, ty = t >> 5;

    const int row0 = blockIdx.x * 64;
    const int nrows = min(64, n - row0);
    const int lim = nrows * 32;
    const float4* Z4 = (const float4*)(Z + (size_t)row0 * 128);
    float4* At4 = (float4*)&At[0][0];
#pragma unroll
    for (int i = 0; i < 4; ++i) {
        int idx = t + 512 * i;
        if (idx < lim) At4[idx] = Z4[idx];
    }
    const float4* W14 = (const float4*)W1;
    ((float4*)&Wb[0][0][0])[t] = W14[t];
    __syncthreads();

    float acc[4][4] = {};
    // ---- GEMM1 ----
    for (int c = 0; c < 8; ++c) {
        const int buf = c & 1;
        float4 wnext;
        if (c < 7) wnext = W14[(c + 1) * 512 + t];
#pragma unroll
        for (int g = 0; g < 4; ++g) {
            float4 w4[4];
#pragma unroll
            for (int kk = 0; kk < 4; ++kk) w4[kk] = *(const float4*)&Wb[buf][g * 4 + kk][tx * 4];
#pragma unroll
            for (int r = 0; r < 4; ++r) {
                float4 a = *(const float4*)&At[ty * 4 + r][c * 16 + g * 4];
                float ar[4] = {a.x, a.y, a.z, a.w};
#pragma unroll
                for (int kk = 0; kk < 4; ++kk) {
                    acc[r][0] = fmaf(ar[kk], w4[kk].x, acc[r][0]);
                    acc[r][1] = fmaf(ar[kk], w4[kk].y, acc[r][1]);
                    acc[r][2] = fmaf(ar[kk], w4[kk].z, acc[r][2]);
                    acc[r][3] = fmaf(ar[kk], w4[kk].w, acc[r][3]);
                }
            }
        }
        if (c < 7) ((float4*)&Wb[buf ^ 1][0][0])[t] = wnext;
        __syncthreads();
    }

    // ---- BN + ReLU, Y -> At, stage W2 chunk 0 ----
    const int c0 = tx * 4;
    const float4* W24 = (const float4*)W2;
    float4 w2pre = W24[t];
    {
        float b1v[4], sc[4], sh[4];
#pragma unroll
        for (int c = 0; c < 4; ++c) {
            b1v[c] = b1[c0 + c];
            float s = gam[c0 + c] * rsqrtf(var[c0 + c] + 1e-5f);
            sc[c] = s;
            sh[c] = bet[c0 + c] - mu[c0 + c] * s;
        }
#pragma unroll
        for (int r = 0; r < 4; ++r) {
            float4 y;
            y.x = fmaxf(fmaf(acc[r][0] + b1v[0], sc[0], sh[0]), 0.f);
            y.y = fmaxf(fmaf(acc[r][1] + b1v[1], sc[1], sh[1]), 0.f);
            y.z = fmaxf(fmaf(acc[r][2] + b1v[2], sc[2], sh[2]), 0.f);
            y.w = fmaxf(fmaf(acc[r][3] + b1v[3], sc[3], sh[3]), 0.f);
            *(float4*)&At[ty * 4 + r][c0] = y;
            acc[r][0] = 0.f; acc[r][1] = 0.f; acc[r][2] = 0.f; acc[r][3] = 0.f;
        }
    }
    ((float4*)&Wb[0][0][0])[t] = w2pre;
    __syncthreads();

    // ---- GEMM2 ----
    for (int c = 0; c < 8; ++c) {
        const int buf = c & 1;
        float4 wnext;
        if (c < 7) wnext = W24[(c + 1) * 512 + t];
#pragma unroll
        for (int g = 0; g < 4; ++g) {
            float4 w4[4];
#pragma unroll
            for (int kk = 0; kk < 4; ++kk) w4[kk] = *(const float4*)&Wb[buf][g * 4 + kk][tx * 4];
#pragma unroll
            for (int r = 0; r < 4; ++r) {
                float4 a = *(const float4*)&At[ty * 4 + r][c * 16 + g * 4];
                float ar[4] = {a.x, a.y, a.z, a.w};
#pragma unroll
                for (int kk = 0; kk < 4; ++kk) {
                    acc[r][0] = fmaf(ar[kk], w4[kk].x, acc[r][0]);
                    acc[r][1] = fmaf(ar[kk], w4[kk].y, acc[r][1]);
                    acc[r][2] = fmaf(ar[kk], w4[kk].z, acc[r][2]);
                    acc[r][3] = fmaf(ar[kk], w4[kk].w, acc[r][3]);
                }
            }
        }
        if (c < 7) ((float4*)&Wb[buf ^ 1][0][0])[t] = wnext;
        __syncthreads();
    }

    // ---- epilogue: relu, write H (and Znext) ----
    float b2v[4];
#pragma unroll
    for (int c = 0; c < 4; ++c) b2v[c] = b2[c0 + c];
    const bool wz = next >= 0;
    const float s = wz ? (1.0f + eps[next]) : 0.0f;
#pragma unroll
    for (int r = 0; r < 4; ++r) {
        int row = row0 + ty * 4 + r;
        if (row < n) {
            float4 o;
            o.x = fmaxf(acc[r][0] + b2v[0], 0.f);
            o.y = fmaxf(acc[r][1] + b2v[1], 0.f);
            o.z = fmaxf(acc[r][2] + b2v[2], 0.f);
            o.w = fmaxf(acc[r][3] + b2v[3], 0.f);
            *(float4*)&H[(size_t)row * 128 + c0] = o;
            if (wz) {
                float4 z;
                z.x = o.x * s; z.y = o.y * s; z.z = o.z * s; z.w = o.w * s;
                *(float4*)&Znext[(size_t)row * 128 + c0] = z;
            }
        }
    }
}

// ---------------------------------------------------------------------------
// Edge kernel: one wave per edge (grid-stride); lane covers 2 columns.
// m = relu(h[src] + edge_attr@W_ee + b_ee) * atten  -> atomic add into Z[dst].
// ---------------------------------------------------------------------------
__global__ __launch_bounds__(256) void edge_kernel(
    const float* __restrict__ h, const int* __restrict__ ei,
    const float* __restrict__ eattr, const float* __restrict__ eatten,
    const float* __restrict__ W_ee, const float* __restrict__ b_ee,
    float* __restrict__ Z, int E)
{
    __shared__ float Wee[16][128];   // 8 KB
    __shared__ float bee[128];
    const int t = threadIdx.x;
    const float4* We4 = (const float4*)W_ee;
    float4* Ws4 = (float4*)&Wee[0][0];
#pragma unroll
    for (int i = 0; i < 2; ++i) Ws4[t + 256 * i] = We4[t + 256 * i];
    if (t < 128) bee[t] = b_ee[t];
    __syncthreads();

    const int lane = t & 63;
    const int c = lane * 2;
    const long wid = (long)blockIdx.x * 4 + (t >> 6);
    const long nw = (long)gridDim.x * 4;
    for (long e = wid; e < E; e += nw) {
        const int src = ei[e];
        const int dst = ei[E + e];
        const float att = eatten[e];
        union { float4 v[4]; float f[16]; } ea;
        const float4* eap = (const float4*)(eattr + e * 16);
        ea.v[0] = eap[0]; ea.v[1] = eap[1]; ea.v[2] = eap[2]; ea.v[3] = eap[3];
        float2 hv = *(const float2*)&h[(size_t)src * 128 + c];
        float e0 = bee[c], e1 = bee[c + 1];
#pragma unroll
        for (int k = 0; k < 16; ++k) {
            float2 w = *(const float2*)&Wee[k][c];
            e0 = fmaf(ea.f[k], w.x, e0);
            e1 = fmaf(ea.f[k], w.y, e1);
        }
        float m0 = fmaxf(hv.x + e0, 0.f) * att;
        float m1 = fmaxf(hv.y + e1, 0.f) * att;
        atomic_add2(&Z[(size_t)dst * 128 + c], m0, m1);
    }
}

extern "C" void kernel_launch(void* const* d_in, const int* in_sizes, int n_in,
                              void* d_out, int out_size, void* d_ws, size_t ws_size,
                              hipStream_t stream)
{
    const float* x      = (const float*)d_in[0];
    const int*   ei     = (const int*)d_in[1];
    // d_in[2] = batch (unused)
    const float* eattr  = (const float*)d_in[3];
    const float* eatten = (const float*)d_in[4];
    const float* W_enc  = (const float*)d_in[5];
    const float* b_enc  = (const float*)d_in[6];
    const float* W_ee   = (const float*)d_in[7];
    const float* b_ee   = (const float*)d_in[8];
    const float* eps    = (const float*)d_in[9];
    const float* W1     = (const float*)d_in[10];
    const float* b1     = (const float*)d_in[11];
    const float* gam    = (const float*)d_in[12];
    const float* bet    = (const float*)d_in[13];
    const float* mu     = (const float*)d_in[14];
    const float* var    = (const float*)d_in[15];
    const float* W2     = (const float*)d_in[16];
    const float* b2     = (const float*)d_in[17];

    const int N = in_sizes[0] / 128;
    const int E = in_sizes[1] / 2;
    const int L = in_sizes[9];

    float* h    = (float*)d_out;   // [N,128]
    float* zbuf = (float*)d_ws;    // [N,128] scratch

    const int tiles = (N + 63) / 64;

    // encoder: h = x@W_enc + b_enc ; zbuf = (1+eps0) h
    gemm_enc<<<tiles, 512, 0, stream>>>(x, W_enc, b_enc, h, zbuf, eps, N);

    for (int i = 0; i < L; ++i) {
        edge_kernel<<<2048, 256, 0, stream>>>(h, ei, eattr, eatten, W_ee, b_ee, zbuf, E);
        const int next = (i + 1 < L) ? (i + 1) : -1;
        gemm_mlp<<<tiles, 512, 0, stream>>>(
            zbuf, W1 + (size_t)i * 128 * 128, b1 + i * 128,
            gam + i * 128, bet + i * 128, mu + i * 128, var + i * 128,
            W2 + (size_t)i * 128 * 128, b2 + i * 128,
            h, zbuf, eps, next, N);
    }
}

// Round 3
// 1268.165 us; speedup vs baseline: 7.2114x; 1.8301x over previous
//
#include <hip/hip_runtime.h>
#include <cstdint>
#include <cstddef>

// ---------------------------------------------------------------------------
// GIN (GINEConv x3) forward, f32.
//   h  = x@W_enc + b_enc                                  (gemm_enc)
//   CSR build: edges bucketed by dst (hist -> scan -> scatter), once per call
//   per layer i:
//     agg:  z[v] = (1+eps_i) h[v] + sum_{e: dst=v} relu(h[src_e]+ea_e)*att_e
//           (one wave per node, no atomics)
//     mlp:  h = relu( relu(BN(z@W1+b1)) @ W2 + b2 )       (gemm_mlp fused)
// ---------------------------------------------------------------------------

// ---- packed-f32x2 atomic with compile-safe fallback (fallback path only) ---
template <class T>
__device__ inline auto add2_impl(T* p, T v, int)
    -> decltype(unsafeAtomicAdd(p, v), void()) {
    unsafeAtomicAdd(p, v);
}
template <class T>
__device__ inline void add2_impl(T* p, T v, long) {
    unsafeAtomicAdd(&p->x, v.x);
    unsafeAtomicAdd(&p->y, v.y);
}
__device__ inline void atomic_add2(float* p, float x, float y) {
    add2_impl(reinterpret_cast<float2*>(p), make_float2(x, y), 0);
}

// ---------------------------------------------------------------------------
// CSR build
// ---------------------------------------------------------------------------
__global__ void zero_cnt(int* __restrict__ cnt, int N)
{
    int i = blockIdx.x * blockDim.x + threadIdx.x;
    if (i < N) cnt[i] = 0;
}

__global__ void hist_kernel(const int* __restrict__ ei, int* __restrict__ cnt, int E)
{
    int i = blockIdx.x * blockDim.x + threadIdx.x;
    const int st = gridDim.x * blockDim.x;
    for (; i < E; i += st) atomicAdd(&cnt[ei[E + i]], 1);
}

// single-block exclusive scan of cnt[0..N) -> off, cur ; off[N]=E
__global__ __launch_bounds__(1024) void scan_kernel(
    const int* __restrict__ cnt, int* __restrict__ off, int* __restrict__ cur,
    int N, int E)
{
    __shared__ int part[1024];
    const int t = threadIdx.x;
    const int chunk = (N + 1023) / 1024;
    const int s0 = min(t * chunk, N), s1 = min(s0 + chunk, N);
    int sum = 0;
    for (int i = s0; i < s1; ++i) sum += cnt[i];
    part[t] = sum;
    __syncthreads();
    for (int d = 1; d < 1024; d <<= 1) {
        int v = (t >= d) ? part[t - d] : 0;
        __syncthreads();
        part[t] += v;
        __syncthreads();
    }
    int base = (t == 0) ? 0 : part[t - 1];
    for (int i = s0; i < s1; ++i) {
        off[i] = base; cur[i] = base;
        base += cnt[i];
    }
    if (t == 0) off[N] = E;
}

__global__ void scatter_kernel(const int* __restrict__ ei, int* __restrict__ cur,
                               int* __restrict__ eids, int E)
{
    int i = blockIdx.x * blockDim.x + threadIdx.x;
    const int st = gridDim.x * blockDim.x;
    for (; i < E; i += st) {
        int pos = atomicAdd(&cur[ei[E + i]], 1);
        eids[pos] = i;
    }
}

// ---------------------------------------------------------------------------
// Aggregation: one wave per node. lane covers 2 cols.
// ---------------------------------------------------------------------------
__global__ __launch_bounds__(256) void agg_kernel(
    const float* __restrict__ h, const int* __restrict__ ei,
    const float* __restrict__ eattr, const float* __restrict__ eatten,
    const int* __restrict__ off, const int* __restrict__ eids,
    const float* __restrict__ W_ee, const float* __restrict__ b_ee,
    float* __restrict__ Z, const float* __restrict__ eps, int layer, int N, int E)
{
    __shared__ float Wee[16][128];   // 8 KB
    __shared__ float bee[128];
    const int t = threadIdx.x;
    const float4* We4 = (const float4*)W_ee;
    float4* Ws4 = (float4*)&Wee[0][0];
#pragma unroll
    for (int i = 0; i < 2; ++i) Ws4[t + 256 * i] = We4[t + 256 * i];
    if (t < 128) bee[t] = b_ee[t];
    __syncthreads();

    const int v = blockIdx.x * 4 + (t >> 6);
    if (v >= N) return;
    const int lane = t & 63;
    const int c = lane * 2;

    float a0 = 0.f, a1 = 0.f;
    const int e0 = off[v], e1 = off[v + 1];
    for (int e = e0; e < e1; ++e) {
        const int eid = eids[e];
        const int src = ei[eid];
        const float att = eatten[eid];
        union { float4 v4[4]; float f[16]; } ea;
        const float4* eap = (const float4*)(eattr + (size_t)eid * 16);
        ea.v4[0] = eap[0]; ea.v4[1] = eap[1]; ea.v4[2] = eap[2]; ea.v4[3] = eap[3];
        const float2 hv = *(const float2*)&h[(size_t)src * 128 + c];
        float d0 = bee[c], d1 = bee[c + 1];
#pragma unroll
        for (int k = 0; k < 16; ++k) {
            float2 w = *(const float2*)&Wee[k][c];
            d0 = fmaf(ea.f[k], w.x, d0);
            d1 = fmaf(ea.f[k], w.y, d1);
        }
        a0 += fmaxf(hv.x + d0, 0.f) * att;
        a1 += fmaxf(hv.y + d1, 0.f) * att;
    }

    const float s = 1.0f + eps[layer];
    const float2 hv = *(const float2*)&h[(size_t)v * 128 + c];
    float2 z;
    z.x = fmaf(s, hv.x, a0);
    z.y = fmaf(s, hv.y, a1);
    *(float2*)&Z[(size_t)v * 128 + c] = z;
}

// ---------------------------------------------------------------------------
// Encoder GEMM: h = A@W + b.  512 thr, 64-row tile, W double-buffered 16-row chunks.
// ---------------------------------------------------------------------------
__global__ __launch_bounds__(512, 4) void gemm_enc(
    const float* __restrict__ A, const float* __restrict__ W,
    const float* __restrict__ bias, float* __restrict__ H, int n)
{
    __shared__ float At[64][128];     // 32 KB
    __shared__ float Wb[2][16][128];  // 16 KB
    const int t = threadIdx.x;
    const int tx = t & 31, ty = t >> 5;

    const int row0 = blockIdx.x * 64;
    const int nrows = min(64, n - row0);
    const int lim = nrows * 32;
    const float4* A4 = (const float4*)(A + (size_t)row0 * 128);
    float4* At4 = (float4*)&At[0][0];
#pragma unroll
    for (int i = 0; i < 4; ++i) {
        int idx = t + 512 * i;
        if (idx < lim) At4[idx] = A4[idx];
    }
    const float4* W4 = (const float4*)W;
    ((float4*)&Wb[0][0][0])[t] = W4[t];
    __syncthreads();

    float acc[4][4] = {};
    for (int c = 0; c < 8; ++c) {
        const int buf = c & 1;
        float4 wnext;
        if (c < 7) wnext = W4[(c + 1) * 512 + t];
#pragma unroll
        for (int g = 0; g < 4; ++g) {
            float4 w4[4];
#pragma unroll
            for (int kk = 0; kk < 4; ++kk) w4[kk] = *(const float4*)&Wb[buf][g * 4 + kk][tx * 4];
#pragma unroll
            for (int r = 0; r < 4; ++r) {
                float4 a = *(const float4*)&At[ty * 4 + r][c * 16 + g * 4];
                float ar[4] = {a.x, a.y, a.z, a.w};
#pragma unroll
                for (int kk = 0; kk < 4; ++kk) {
                    acc[r][0] = fmaf(ar[kk], w4[kk].x, acc[r][0]);
                    acc[r][1] = fmaf(ar[kk], w4[kk].y, acc[r][1]);
                    acc[r][2] = fmaf(ar[kk], w4[kk].z, acc[r][2]);
                    acc[r][3] = fmaf(ar[kk], w4[kk].w, acc[r][3]);
                }
            }
        }
        if (c < 7) ((float4*)&Wb[buf ^ 1][0][0])[t] = wnext;
        __syncthreads();
    }

    const int c0 = tx * 4;
    float bv[4];
#pragma unroll
    for (int c = 0; c < 4; ++c) bv[c] = bias[c0 + c];
#pragma unroll
    for (int r = 0; r < 4; ++r) {
        int row = row0 + ty * 4 + r;
        if (row < n) {
            float4 o;
            o.x = acc[r][0] + bv[0]; o.y = acc[r][1] + bv[1];
            o.z = acc[r][2] + bv[2]; o.w = acc[r][3] + bv[3];
            *(float4*)&H[(size_t)row * 128 + c0] = o;
        }
    }
}

// ---------------------------------------------------------------------------
// Fused MLP: h = relu( relu(BN(Z@W1+b1)) @ W2 + b2 ).
// ---------------------------------------------------------------------------
__global__ __launch_bounds__(512, 4) void gemm_mlp(
    const float* __restrict__ Z,
    const float* __restrict__ W1, const float* __restrict__ b1,
    const float* __restrict__ gam, const float* __restrict__ bet,
    const float* __restrict__ mu, const float* __restrict__ var,
    const float* __restrict__ W2, const float* __restrict__ b2,
    float* __restrict__ H, int n)
{
    __shared__ float At[64][128];     // 32 KB; holds A, then Y
    __shared__ float Wb[2][16][128];  // 16 KB
    const int t = threadIdx.x;
    const int tx = t & 31, ty = t >> 5;

    const int row0 = blockIdx.x * 64;
    const int nrows = min(64, n - row0);
    const int lim = nrows * 32;
    const float4* Z4 = (const float4*)(Z + (size_t)row0 * 128);
    float4* At4 = (float4*)&At[0][0];
#pragma unroll
    for (int i = 0; i < 4; ++i) {
        int idx = t + 512 * i;
        if (idx < lim) At4[idx] = Z4[idx];
    }
    const float4* W14 = (const float4*)W1;
    ((float4*)&Wb[0][0][0])[t] = W14[t];
    __syncthreads();

    float acc[4][4] = {};
    // ---- GEMM1 ----
    for (int c = 0; c < 8; ++c) {
        const int buf = c & 1;
        float4 wnext;
        if (c < 7) wnext = W14[(c + 1) * 512 + t];
#pragma unroll
        for (int g = 0; g < 4; ++g) {
            float4 w4[4];
#pragma unroll
            for (int kk = 0; kk < 4; ++kk) w4[kk] = *(const float4*)&Wb[buf][g * 4 + kk][tx * 4];
#pragma unroll
            for (int r = 0; r < 4; ++r) {
                float4 a = *(const float4*)&At[ty * 4 + r][c * 16 + g * 4];
                float ar[4] = {a.x, a.y, a.z, a.w};
#pragma unroll
                for (int kk = 0; kk < 4; ++kk) {
                    acc[r][0] = fmaf(ar[kk], w4[kk].x, acc[r][0]);
                    acc[r][1] = fmaf(ar[kk], w4[kk].y, acc[r][1]);
                    acc[r][2] = fmaf(ar[kk], w4[kk].z, acc[r][2]);
                    acc[r][3] = fmaf(ar[kk], w4[kk].w, acc[r][3]);
                }
            }
        }
        if (c < 7) ((float4*)&Wb[buf ^ 1][0][0])[t] = wnext;
        __syncthreads();
    }

    // ---- BN + ReLU, Y -> At, stage W2 chunk 0 ----
    const int c0 = tx * 4;
    const float4* W24 = (const float4*)W2;
    float4 w2pre = W24[t];
    {
        float b1v[4], sc[4], sh[4];
#pragma unroll
        for (int c = 0; c < 4; ++c) {
            b1v[c] = b1[c0 + c];
            float s = gam[c0 + c] * rsqrtf(var[c0 + c] + 1e-5f);
            sc[c] = s;
            sh[c] = bet[c0 + c] - mu[c0 + c] * s;
        }
#pragma unroll
        for (int r = 0; r < 4; ++r) {
            float4 y;
            y.x = fmaxf(fmaf(acc[r][0] + b1v[0], sc[0], sh[0]), 0.f);
            y.y = fmaxf(fmaf(acc[r][1] + b1v[1], sc[1], sh[1]), 0.f);
            y.z = fmaxf(fmaf(acc[r][2] + b1v[2], sc[2], sh[2]), 0.f);
            y.w = fmaxf(fmaf(acc[r][3] + b1v[3], sc[3], sh[3]), 0.f);
            *(float4*)&At[ty * 4 + r][c0] = y;
            acc[r][0] = 0.f; acc[r][1] = 0.f; acc[r][2] = 0.f; acc[r][3] = 0.f;
        }
    }
    ((float4*)&Wb[0][0][0])[t] = w2pre;
    __syncthreads();

    // ---- GEMM2 ----
    for (int c = 0; c < 8; ++c) {
        const int buf = c & 1;
        float4 wnext;
        if (c < 7) wnext = W24[(c + 1) * 512 + t];
#pragma unroll
        for (int g = 0; g < 4; ++g) {
            float4 w4[4];
#pragma unroll
            for (int kk = 0; kk < 4; ++kk) w4[kk] = *(const float4*)&Wb[buf][g * 4 + kk][tx * 4];
#pragma unroll
            for (int r = 0; r < 4; ++r) {
                float4 a = *(const float4*)&At[ty * 4 + r][c * 16 + g * 4];
                float ar[4] = {a.x, a.y, a.z, a.w};
#pragma unroll
                for (int kk = 0; kk < 4; ++kk) {
                    acc[r][0] = fmaf(ar[kk], w4[kk].x, acc[r][0]);
                    acc[r][1] = fmaf(ar[kk], w4[kk].y, acc[r][1]);
                    acc[r][2] = fmaf(ar[kk], w4[kk].z, acc[r][2]);
                    acc[r][3] = fmaf(ar[kk], w4[kk].w, acc[r][3]);
                }
            }
        }
        if (c < 7) ((float4*)&Wb[buf ^ 1][0][0])[t] = wnext;
        __syncthreads();
    }

    float b2v[4];
#pragma unroll
    for (int c = 0; c < 4; ++c) b2v[c] = b2[c0 + c];
#pragma unroll
    for (int r = 0; r < 4; ++r) {
        int row = row0 + ty * 4 + r;
        if (row < n) {
            float4 o;
            o.x = fmaxf(acc[r][0] + b2v[0], 0.f);
            o.y = fmaxf(acc[r][1] + b2v[1], 0.f);
            o.z = fmaxf(acc[r][2] + b2v[2], 0.f);
            o.w = fmaxf(acc[r][3] + b2v[3], 0.f);
            *(float4*)&H[(size_t)row * 128 + c0] = o;
        }
    }
}

// ---------------------------------------------------------------------------
// Fallback path (ws too small for CSR): scale_init + atomic edge kernel
// ---------------------------------------------------------------------------
__global__ void scale_init(const float* __restrict__ h, float* __restrict__ z,
                           const float* __restrict__ eps, int layer, int n4)
{
    const float s = 1.0f + eps[layer];
    int i = blockIdx.x * blockDim.x + threadIdx.x;
    const int stride = gridDim.x * blockDim.x;
    const float4* h4 = (const float4*)h;
    float4* z4 = (float4*)z;
    for (; i < n4; i += stride) {
        float4 v = h4[i];
        v.x *= s; v.y *= s; v.z *= s; v.w *= s;
        z4[i] = v;
    }
}

__global__ __launch_bounds__(256) void edge_atomic(
    const float* __restrict__ h, const int* __restrict__ ei,
    const float* __restrict__ eattr, const float* __restrict__ eatten,
    const float* __restrict__ W_ee, const float* __restrict__ b_ee,
    float* __restrict__ Z, int E)
{
    __shared__ float Wee[16][128];
    __shared__ float bee[128];
    const int t = threadIdx.x;
    const float4* We4 = (const float4*)W_ee;
    float4* Ws4 = (float4*)&Wee[0][0];
#pragma unroll
    for (int i = 0; i < 2; ++i) Ws4[t + 256 * i] = We4[t + 256 * i];
    if (t < 128) bee[t] = b_ee[t];
    __syncthreads();

    const int lane = t & 63;
    const int c = lane * 2;
    const long wid = (long)blockIdx.x * 4 + (t >> 6);
    const long nw = (long)gridDim.x * 4;
    for (long e = wid; e < E; e += nw) {
        const int src = ei[e];
        const int dst = ei[E + e];
        const float att = eatten[e];
        union { float4 v4[4]; float f[16]; } ea;
        const float4* eap = (const float4*)(eattr + e * 16);
        ea.v4[0] = eap[0]; ea.v4[1] = eap[1]; ea.v4[2] = eap[2]; ea.v4[3] = eap[3];
        float2 hv = *(const float2*)&h[(size_t)src * 128 + c];
        float e0 = bee[c], e1 = bee[c + 1];
#pragma unroll
        for (int k = 0; k < 16; ++k) {
            float2 w = *(const float2*)&Wee[k][c];
            e0 = fmaf(ea.f[k], w.x, e0);
            e1 = fmaf(ea.f[k], w.y, e1);
        }
        float m0 = fmaxf(hv.x + e0, 0.f) * att;
        float m1 = fmaxf(hv.y + e1, 0.f) * att;
        atomic_add2(&Z[(size_t)dst * 128 + c], m0, m1);
    }
}

extern "C" void kernel_launch(void* const* d_in, const int* in_sizes, int n_in,
                              void* d_out, int out_size, void* d_ws, size_t ws_size,
                              hipStream_t stream)
{
    const float* x      = (const float*)d_in[0];
    const int*   ei     = (const int*)d_in[1];
    // d_in[2] = batch (unused)
    const float* eattr  = (const float*)d_in[3];
    const float* eatten = (const float*)d_in[4];
    const float* W_enc  = (const float*)d_in[5];
    const float* b_enc  = (const float*)d_in[6];
    const float* W_ee   = (const float*)d_in[7];
    const float* b_ee   = (const float*)d_in[8];
    const float* eps    = (const float*)d_in[9];
    const float* W1     = (const float*)d_in[10];
    const float* b1     = (const float*)d_in[11];
    const float* gam    = (const float*)d_in[12];
    const float* bet    = (const float*)d_in[13];
    const float* mu     = (const float*)d_in[14];
    const float* var    = (const float*)d_in[15];
    const float* W2     = (const float*)d_in[16];
    const float* b2     = (const float*)d_in[17];

    const int N = in_sizes[0] / 128;
    const int E = in_sizes[1] / 2;
    const int L = in_sizes[9];

    float* h    = (float*)d_out;   // [N,128]
    float* zbuf = (float*)d_ws;    // [N,128]

    // CSR scratch behind zbuf
    const size_t zb = ((size_t)N * 128 * sizeof(float) + 255) & ~(size_t)255;
    int* off  = (int*)((char*)d_ws + zb);   // N+1
    int* cur  = off + (N + 1);              // N
    int* cnt  = cur + N;                    // N
    int* eids = cnt + N;                    // E
    const size_t needed = zb + sizeof(int) * ((size_t)3 * N + 1 + (size_t)E);
    const bool use_csr = ws_size >= needed;

    const int tiles = (N + 63) / 64;

    gemm_enc<<<tiles, 512, 0, stream>>>(x, W_enc, b_enc, h, N);

    if (use_csr) {
        zero_cnt<<<(N + 255) / 256, 256, 0, stream>>>(cnt, N);
        hist_kernel<<<1024, 256, 0, stream>>>(ei, cnt, E);
        scan_kernel<<<1, 1024, 0, stream>>>(cnt, off, cur, N, E);
        scatter_kernel<<<1024, 256, 0, stream>>>(ei, cur, eids, E);
    }

    for (int i = 0; i < L; ++i) {
        if (use_csr) {
            agg_kernel<<<(N + 3) / 4, 256, 0, stream>>>(
                h, ei, eattr, eatten, off, eids, W_ee, b_ee, zbuf, eps, i, N, E);
        } else {
            scale_init<<<2048, 256, 0, stream>>>(h, zbuf, eps, i, N * 128 / 4);
            edge_atomic<<<2048, 256, 0, stream>>>(h, ei, eattr, eatten, W_ee, b_ee, zbuf, E);
        }
        gemm_mlp<<<tiles, 512, 0, stream>>>(
            zbuf, W1 + (size_t)i * 128 * 128, b1 + i * 128,
            gam + i * 128, bet + i * 128, mu + i * 128, var + i * 128,
            W2 + (size_t)i * 128 * 128, b2 + i * 128,
            h, N);
    }
}

// Round 4
// 1062.502 us; speedup vs baseline: 8.6072x; 1.1936x over previous
//
#include <hip/hip_runtime.h>
#include <cstdint>
#include <cstddef>

// ---------------------------------------------------------------------------
// GIN (GINEConv x3) forward, f32.
//   h  = x@W_enc + b_enc                                  (gemm_enc)
//   CSR build: edges bucketed by dst (hist -> scan -> scatter -> permute)
//   per layer i:
//     agg:  z[v] = (1+eps_i) h[v] + sum_{e: dst=v} relu(h[src_e]+ea_e)*att_e
//           one wave per node, W_ee in registers, 4-edge unrolled gather
//     mlp:  h = relu( relu(BN(z@W1+b1)) @ W2 + b2 )       (gemm_mlp fused)
// ---------------------------------------------------------------------------

// ---- packed-f32x2 atomic with compile-safe fallback (fallback path only) ---
template <class T>
__device__ inline auto add2_impl(T* p, T v, int)
    -> decltype(unsafeAtomicAdd(p, v), void()) {
    unsafeAtomicAdd(p, v);
}
template <class T>
__device__ inline void add2_impl(T* p, T v, long) {
    unsafeAtomicAdd(&p->x, v.x);
    unsafeAtomicAdd(&p->y, v.y);
}
__device__ inline void atomic_add2(float* p, float x, float y) {
    add2_impl(reinterpret_cast<float2*>(p), make_float2(x, y), 0);
}

// ---------------------------------------------------------------------------
// CSR build
// ---------------------------------------------------------------------------
__global__ void zero_cnt(int* __restrict__ cnt, int N)
{
    int i = blockIdx.x * blockDim.x + threadIdx.x;
    if (i < N) cnt[i] = 0;
}

__global__ void hist_kernel(const int* __restrict__ ei, int* __restrict__ cnt, int E)
{
    int i = blockIdx.x * blockDim.x + threadIdx.x;
    const int st = gridDim.x * blockDim.x;
    for (; i < E; i += st) atomicAdd(&cnt[ei[E + i]], 1);
}

// single-block exclusive scan of cnt[0..N) -> off, cur ; off[N]=E
__global__ __launch_bounds__(1024) void scan_kernel(
    const int* __restrict__ cnt, int* __restrict__ off, int* __restrict__ cur,
    int N, int E)
{
    __shared__ int part[1024];
    const int t = threadIdx.x;
    const int chunk = (N + 1023) / 1024;
    const int s0 = min(t * chunk, N), s1 = min(s0 + chunk, N);
    int sum = 0;
    for (int i = s0; i < s1; ++i) sum += cnt[i];
    part[t] = sum;
    __syncthreads();
    for (int d = 1; d < 1024; d <<= 1) {
        int v = (t >= d) ? part[t - d] : 0;
        __syncthreads();
        part[t] += v;
        __syncthreads();
    }
    int base = (t == 0) ? 0 : part[t - 1];
    for (int i = s0; i < s1; ++i) {
        off[i] = base; cur[i] = base;
        base += cnt[i];
    }
    if (t == 0) off[N] = E;
}

__global__ void scatter_kernel(const int* __restrict__ ei, int* __restrict__ cur,
                               int* __restrict__ eids, int E)
{
    int i = blockIdx.x * blockDim.x + threadIdx.x;
    const int st = gridDim.x * blockDim.x;
    for (; i < E; i += st) {
        int pos = atomicAdd(&cur[ei[E + i]], 1);
        eids[pos] = i;
    }
}

// permute edge payloads into CSR slot order: srcp/attp (+optionally ea rows)
__global__ void permute_kernel(
    const int* __restrict__ ei, const float* __restrict__ eattr,
    const float* __restrict__ eatten, const int* __restrict__ eids,
    int* __restrict__ srcp, float* __restrict__ attp, float4* __restrict__ eap,
    int E, int write_ea)
{
    int i = blockIdx.x * blockDim.x + threadIdx.x;
    const int st = gridDim.x * blockDim.x;
    const int tot = E * 4;
    for (; i < tot; i += st) {
        const int slot = i >> 2, part = i & 3;
        const int eid = eids[slot];
        if (write_ea) eap[i] = ((const float4*)eattr)[(size_t)eid * 4 + part];
        if (part == 0) { srcp[slot] = ei[eid]; attp[slot] = eatten[eid]; }
    }
}

// ---------------------------------------------------------------------------
// Aggregation: one wave per node, lane owns 2 cols. W_ee slice in registers.
// EA=true: edge-attr rows pre-permuted (sequential); else via eids gather.
// ---------------------------------------------------------------------------
template <bool EA>
__global__ __launch_bounds__(256) void agg_gather(
    const float* __restrict__ h, const int* __restrict__ srcp,
    const float* __restrict__ attp, const float4* __restrict__ eap,
    const int* __restrict__ eids, const float* __restrict__ eattr,
    const int* __restrict__ off,
    const float* __restrict__ W_ee, const float* __restrict__ b_ee,
    float* __restrict__ Z, const float* __restrict__ eps, int layer, int N)
{
    const int t = threadIdx.x;
    const int lane = t & 63;
    const int c = lane * 2;
    float2 w[16];
#pragma unroll
    for (int k = 0; k < 16; ++k) w[k] = *(const float2*)&W_ee[k * 128 + c];
    const float2 bv = *(const float2*)&b_ee[c];

    const int v = blockIdx.x * 4 + (t >> 6);
    if (v >= N) return;

    const int e0 = off[v], e1 = off[v + 1];
    float a0 = 0.f, a1 = 0.f;
    int e = e0;
    for (; e + 4 <= e1; e += 4) {
        int s[4]; float at[4];
#pragma unroll
        for (int u = 0; u < 4; ++u) { s[u] = srcp[e + u]; at[u] = attp[e + u]; }
        float2 hv[4];
#pragma unroll
        for (int u = 0; u < 4; ++u)
            hv[u] = *(const float2*)&h[(size_t)s[u] * 128 + c];
        float4 ev[4][4];
#pragma unroll
        for (int u = 0; u < 4; ++u) {
            const float4* e4;
            if constexpr (EA) e4 = eap + (size_t)(e + u) * 4;
            else e4 = (const float4*)(eattr + (size_t)eids[e + u] * 16);
#pragma unroll
            for (int q = 0; q < 4; ++q) ev[u][q] = e4[q];
        }
#pragma unroll
        for (int u = 0; u < 4; ++u) {
            const float* ef = (const float*)&ev[u][0];
            float d0 = bv.x, d1 = bv.y;
#pragma unroll
            for (int k = 0; k < 16; ++k) {
                d0 = fmaf(ef[k], w[k].x, d0);
                d1 = fmaf(ef[k], w[k].y, d1);
            }
            a0 += fmaxf(hv[u].x + d0, 0.f) * at[u];
            a1 += fmaxf(hv[u].y + d1, 0.f) * at[u];
        }
    }
    for (; e < e1; ++e) {
        const int s = srcp[e];
        const float at = attp[e];
        const float2 hv = *(const float2*)&h[(size_t)s * 128 + c];
        const float4* e4;
        if constexpr (EA) e4 = eap + (size_t)e * 4;
        else e4 = (const float4*)(eattr + (size_t)eids[e] * 16);
        float4 ev[4];
#pragma unroll
        for (int q = 0; q < 4; ++q) ev[q] = e4[q];
        const float* ef = (const float*)&ev[0];
        float d0 = bv.x, d1 = bv.y;
#pragma unroll
        for (int k = 0; k < 16; ++k) {
            d0 = fmaf(ef[k], w[k].x, d0);
            d1 = fmaf(ef[k], w[k].y, d1);
        }
        a0 += fmaxf(hv.x + d0, 0.f) * at;
        a1 += fmaxf(hv.y + d1, 0.f) * at;
    }

    const float sc = 1.0f + eps[layer];
    const float2 hv = *(const float2*)&h[(size_t)v * 128 + c];
    float2 z;
    z.x = fmaf(sc, hv.x, a0);
    z.y = fmaf(sc, hv.y, a1);
    *(float2*)&Z[(size_t)v * 128 + c] = z;
}

// ---------------------------------------------------------------------------
// Tier-0 aggregation fallback (round-3 style: eids indirection, LDS W_ee)
// ---------------------------------------------------------------------------
__global__ __launch_bounds__(256) void agg_kernel(
    const float* __restrict__ h, const int* __restrict__ ei,
    const float* __restrict__ eattr, const float* __restrict__ eatten,
    const int* __restrict__ off, const int* __restrict__ eids,
    const float* __restrict__ W_ee, const float* __restrict__ b_ee,
    float* __restrict__ Z, const float* __restrict__ eps, int layer, int N, int E)
{
    __shared__ float Wee[16][128];
    __shared__ float bee[128];
    const int t = threadIdx.x;
    const float4* We4 = (const float4*)W_ee;
    float4* Ws4 = (float4*)&Wee[0][0];
#pragma unroll
    for (int i = 0; i < 2; ++i) Ws4[t + 256 * i] = We4[t + 256 * i];
    if (t < 128) bee[t] = b_ee[t];
    __syncthreads();

    const int v = blockIdx.x * 4 + (t >> 6);
    if (v >= N) return;
    const int lane = t & 63;
    const int c = lane * 2;

    float a0 = 0.f, a1 = 0.f;
    const int e0 = off[v], e1 = off[v + 1];
    for (int e = e0; e < e1; ++e) {
        const int eid = eids[e];
        const int src = ei[eid];
        const float att = eatten[eid];
        union { float4 v4[4]; float f[16]; } ea;
        const float4* eap = (const float4*)(eattr + (size_t)eid * 16);
        ea.v4[0] = eap[0]; ea.v4[1] = eap[1]; ea.v4[2] = eap[2]; ea.v4[3] = eap[3];
        const float2 hv = *(const float2*)&h[(size_t)src * 128 + c];
        float d0 = bee[c], d1 = bee[c + 1];
#pragma unroll
        for (int k = 0; k < 16; ++k) {
            float2 w = *(const float2*)&Wee[k][c];
            d0 = fmaf(ea.f[k], w.x, d0);
            d1 = fmaf(ea.f[k], w.y, d1);
        }
        a0 += fmaxf(hv.x + d0, 0.f) * att;
        a1 += fmaxf(hv.y + d1, 0.f) * att;
    }

    const float s = 1.0f + eps[layer];
    const float2 hv = *(const float2*)&h[(size_t)v * 128 + c];
    float2 z;
    z.x = fmaf(s, hv.x, a0);
    z.y = fmaf(s, hv.y, a1);
    *(float2*)&Z[(size_t)v * 128 + c] = z;
}

// ---------------------------------------------------------------------------
// Encoder GEMM: h = A@W + b.  512 thr, 64-row tile, W double-buffered.
// ---------------------------------------------------------------------------
__global__ __launch_bounds__(512, 4) void gemm_enc(
    const float* __restrict__ A, const float* __restrict__ W,
    const float* __restrict__ bias, float* __restrict__ H, int n)
{
    __shared__ float At[64][128];
    __shared__ float Wb[2][16][128];
    const int t = threadIdx.x;
    const int tx = t & 31, ty = t >> 5;

    const int row0 = blockIdx.x * 64;
    const int nrows = min(64, n - row0);
    const int lim = nrows * 32;
    const float4* A4 = (const float4*)(A + (size_t)row0 * 128);
    float4* At4 = (float4*)&At[0][0];
#pragma unroll
    for (int i = 0; i < 4; ++i) {
        int idx = t + 512 * i;
        if (idx < lim) At4[idx] = A4[idx];
    }
    const float4* W4 = (const float4*)W;
    ((float4*)&Wb[0][0][0])[t] = W4[t];
    __syncthreads();

    float acc[4][4] = {};
    for (int c = 0; c < 8; ++c) {
        const int buf = c & 1;
        float4 wnext;
        if (c < 7) wnext = W4[(c + 1) * 512 + t];
#pragma unroll
        for (int g = 0; g < 4; ++g) {
            float4 w4[4];
#pragma unroll
            for (int kk = 0; kk < 4; ++kk) w4[kk] = *(const float4*)&Wb[buf][g * 4 + kk][tx * 4];
#pragma unroll
            for (int r = 0; r < 4; ++r) {
                float4 a = *(const float4*)&At[ty * 4 + r][c * 16 + g * 4];
                float ar[4] = {a.x, a.y, a.z, a.w};
#pragma unroll
                for (int kk = 0; kk < 4; ++kk) {
                    acc[r][0] = fmaf(ar[kk], w4[kk].x, acc[r][0]);
                    acc[r][1] = fmaf(ar[kk], w4[kk].y, acc[r][1]);
                    acc[r][2] = fmaf(ar[kk], w4[kk].z, acc[r][2]);
                    acc[r][3] = fmaf(ar[kk], w4[kk].w, acc[r][3]);
                }
            }
        }
        if (c < 7) ((float4*)&Wb[buf ^ 1][0][0])[t] = wnext;
        __syncthreads();
    }

    const int c0 = tx * 4;
    float bvv[4];
#pragma unroll
    for (int c = 0; c < 4; ++c) bvv[c] = bias[c0 + c];
#pragma unroll
    for (int r = 0; r < 4; ++r) {
        int row = row0 + ty * 4 + r;
        if (row < n) {
            float4 o;
            o.x = acc[r][0] + bvv[0]; o.y = acc[r][1] + bvv[1];
            o.z = acc[r][2] + bvv[2]; o.w = acc[r][3] + bvv[3];
            *(float4*)&H[(size_t)row * 128 + c0] = o;
        }
    }
}

// ---------------------------------------------------------------------------
// Fused MLP: h = relu( relu(BN(Z@W1+b1)) @ W2 + b2 ).
// ---------------------------------------------------------------------------
__global__ __launch_bounds__(512, 4) void gemm_mlp(
    const float* __restrict__ Z,
    const float* __restrict__ W1, const float* __restrict__ b1,
    const float* __restrict__ gam, const float* __restrict__ bet,
    const float* __restrict__ mu, const float* __restrict__ var,
    const float* __restrict__ W2, const float* __restrict__ b2,
    float* __restrict__ H, int n)
{
    __shared__ float At[64][128];
    __shared__ float Wb[2][16][128];
    const int t = threadIdx.x;
    const int tx = t & 31, ty = t >> 5;

    const int row0 = blockIdx.x * 64;
    const int nrows = min(64, n - row0);
    const int lim = nrows * 32;
    const float4* Z4 = (const float4*)(Z + (size_t)row0 * 128);
    float4* At4 = (float4*)&At[0][0];
#pragma unroll
    for (int i = 0; i < 4; ++i) {
        int idx = t + 512 * i;
        if (idx < lim) At4[idx] = Z4[idx];
    }
    const float4* W14 = (const float4*)W1;
    ((float4*)&Wb[0][0][0])[t] = W14[t];
    __syncthreads();

    float acc[4][4] = {};
    for (int c = 0; c < 8; ++c) {
        const int buf = c & 1;
        float4 wnext;
        if (c < 7) wnext = W14[(c + 1) * 512 + t];
#pragma unroll
        for (int g = 0; g < 4; ++g) {
            float4 w4[4];
#pragma unroll
            for (int kk = 0; kk < 4; ++kk) w4[kk] = *(const float4*)&Wb[buf][g * 4 + kk][tx * 4];
#pragma unroll
            for (int r = 0; r < 4; ++r) {
                float4 a = *(const float4*)&At[ty * 4 + r][c * 16 + g * 4];
                float ar[4] = {a.x, a.y, a.z, a.w};
#pragma unroll
                for (int kk = 0; kk < 4; ++kk) {
                    acc[r][0] = fmaf(ar[kk], w4[kk].x, acc[r][0]);
                    acc[r][1] = fmaf(ar[kk], w4[kk].y, acc[r][1]);
                    acc[r][2] = fmaf(ar[kk], w4[kk].z, acc[r][2]);
                    acc[r][3] = fmaf(ar[kk], w4[kk].w, acc[r][3]);
                }
            }
        }
        if (c < 7) ((float4*)&Wb[buf ^ 1][0][0])[t] = wnext;
        __syncthreads();
    }

    const int c0 = tx * 4;
    const float4* W24 = (const float4*)W2;
    float4 w2pre = W24[t];
    {
        float b1v[4], sc[4], sh[4];
#pragma unroll
        for (int c = 0; c < 4; ++c) {
            b1v[c] = b1[c0 + c];
            float s = gam[c0 + c] * rsqrtf(var[c0 + c] + 1e-5f);
            sc[c] = s;
            sh[c] = bet[c0 + c] - mu[c0 + c] * s;
        }
#pragma unroll
        for (int r = 0; r < 4; ++r) {
            float4 y;
            y.x = fmaxf(fmaf(acc[r][0] + b1v[0], sc[0], sh[0]), 0.f);
            y.y = fmaxf(fmaf(acc[r][1] + b1v[1], sc[1], sh[1]), 0.f);
            y.z = fmaxf(fmaf(acc[r][2] + b1v[2], sc[2], sh[2]), 0.f);
            y.w = fmaxf(fmaf(acc[r][3] + b1v[3], sc[3], sh[3]), 0.f);
            *(float4*)&At[ty * 4 + r][c0] = y;
            acc[r][0] = 0.f; acc[r][1] = 0.f; acc[r][2] = 0.f; acc[r][3] = 0.f;
        }
    }
    ((float4*)&Wb[0][0][0])[t] = w2pre;
    __syncthreads();

    for (int c = 0; c < 8; ++c) {
        const int buf = c & 1;
        float4 wnext;
        if (c < 7) wnext = W24[(c + 1) * 512 + t];
#pragma unroll
        for (int g = 0; g < 4; ++g) {
            float4 w4[4];
#pragma unroll
            for (int kk = 0; kk < 4; ++kk) w4[kk] = *(const float4*)&Wb[buf][g * 4 + kk][tx * 4];
#pragma unroll
            for (int r = 0; r < 4; ++r) {
                float4 a = *(const float4*)&At[ty * 4 + r][c * 16 + g * 4];
                float ar[4] = {a.x, a.y, a.z, a.w};
#pragma unroll
                for (int kk = 0; kk < 4; ++kk) {
                    acc[r][0] = fmaf(ar[kk], w4[kk].x, acc[r][0]);
                    acc[r][1] = fmaf(ar[kk], w4[kk].y, acc[r][1]);
                    acc[r][2] = fmaf(ar[kk], w4[kk].z, acc[r][2]);
                    acc[r][3] = fmaf(ar[kk], w4[kk].w, acc[r][3]);
                }
            }
        }
        if (c < 7) ((float4*)&Wb[buf ^ 1][0][0])[t] = wnext;
        __syncthreads();
    }

    float b2v[4];
#pragma unroll
    for (int c = 0; c < 4; ++c) b2v[c] = b2[c0 + c];
#pragma unroll
    for (int r = 0; r < 4; ++r) {
        int row = row0 + ty * 4 + r;
        if (row < n) {
            float4 o;
            o.x = fmaxf(acc[r][0] + b2v[0], 0.f);
            o.y = fmaxf(acc[r][1] + b2v[1], 0.f);
            o.z = fmaxf(acc[r][2] + b2v[2], 0.f);
            o.w = fmaxf(acc[r][3] + b2v[3], 0.f);
            *(float4*)&H[(size_t)row * 128 + c0] = o;
        }
    }
}

// ---------------------------------------------------------------------------
// Last-resort fallback: scale_init + atomic edge kernel
// ---------------------------------------------------------------------------
__global__ void scale_init(const float* __restrict__ h, float* __restrict__ z,
                           const float* __restrict__ eps, int layer, int n4)
{
    const float s = 1.0f + eps[layer];
    int i = blockIdx.x * blockDim.x + threadIdx.x;
    const int stride = gridDim.x * blockDim.x;
    const float4* h4 = (const float4*)h;
    float4* z4 = (float4*)z;
    for (; i < n4; i += stride) {
        float4 v = h4[i];
        v.x *= s; v.y *= s; v.z *= s; v.w *= s;
        z4[i] = v;
    }
}

__global__ __launch_bounds__(256) void edge_atomic(
    const float* __restrict__ h, const int* __restrict__ ei,
    const float* __restrict__ eattr, const float* __restrict__ eatten,
    const float* __restrict__ W_ee, const float* __restrict__ b_ee,
    float* __restrict__ Z, int E)
{
    __shared__ float Wee[16][128];
    __shared__ float bee[128];
    const int t = threadIdx.x;
    const float4* We4 = (const float4*)W_ee;
    float4* Ws4 = (float4*)&Wee[0][0];
#pragma unroll
    for (int i = 0; i < 2; ++i) Ws4[t + 256 * i] = We4[t + 256 * i];
    if (t < 128) bee[t] = b_ee[t];
    __syncthreads();

    const int lane = t & 63;
    const int c = lane * 2;
    const long wid = (long)blockIdx.x * 4 + (t >> 6);
    const long nw = (long)gridDim.x * 4;
    for (long e = wid; e < E; e += nw) {
        const int src = ei[e];
        const int dst = ei[E + e];
        const float att = eatten[e];
        union { float4 v4[4]; float f[16]; } ea;
        const float4* eap = (const float4*)(eattr + e * 16);
        ea.v4[0] = eap[0]; ea.v4[1] = eap[1]; ea.v4[2] = eap[2]; ea.v4[3] = eap[3];
        float2 hv = *(const float2*)&h[(size_t)src * 128 + c];
        float e0 = bee[c], e1 = bee[c + 1];
#pragma unroll
        for (int k = 0; k < 16; ++k) {
            float2 w = *(const float2*)&Wee[k][c];
            e0 = fmaf(ea.f[k], w.x, e0);
            e1 = fmaf(ea.f[k], w.y, e1);
        }
        float m0 = fmaxf(hv.x + e0, 0.f) * att;
        float m1 = fmaxf(hv.y + e1, 0.f) * att;
        atomic_add2(&Z[(size_t)dst * 128 + c], m0, m1);
    }
}

extern "C" void kernel_launch(void* const* d_in, const int* in_sizes, int n_in,
                              void* d_out, int out_size, void* d_ws, size_t ws_size,
                              hipStream_t stream)
{
    const float* x      = (const float*)d_in[0];
    const int*   ei     = (const int*)d_in[1];
    // d_in[2] = batch (unused)
    const float* eattr  = (const float*)d_in[3];
    const float* eatten = (const float*)d_in[4];
    const float* W_enc  = (const float*)d_in[5];
    const float* b_enc  = (const float*)d_in[6];
    const float* W_ee   = (const float*)d_in[7];
    const float* b_ee   = (const float*)d_in[8];
    const float* eps    = (const float*)d_in[9];
    const float* W1     = (const float*)d_in[10];
    const float* b1     = (const float*)d_in[11];
    const float* gam    = (const float*)d_in[12];
    const float* bet    = (const float*)d_in[13];
    const float* mu     = (const float*)d_in[14];
    const float* var    = (const float*)d_in[15];
    const float* W2     = (const float*)d_in[16];
    const float* b2     = (const float*)d_in[17];

    const int N = in_sizes[0] / 128;
    const int E = in_sizes[1] / 2;
    const int L = in_sizes[9];

    float* h = (float*)d_out;   // [N,128]

    // workspace layout
    char* p = (char*)d_ws;
    float* zbuf = (float*)p;            p += ((size_t)N * 128 * 4 + 255) & ~(size_t)255;
    int* off  = (int*)p;                p += 4 * (size_t)(N + 1);
    int* cur  = (int*)p;                p += 4 * (size_t)N;
    int* cnt  = (int*)p;                p += 4 * (size_t)N;
    int* eids = (int*)p;                p += 4 * (size_t)E;
    const size_t need_csr = (size_t)(p - (char*)d_ws);
    int*   srcp = (int*)p;              p += 4 * (size_t)E;
    float* attp = (float*)p;            p += 4 * (size_t)E;
    const size_t need_perm = (size_t)(p - (char*)d_ws);
    p = (char*)(((uintptr_t)p + 15) & ~(uintptr_t)15);
    float4* eap = (float4*)p;           p += 64 * (size_t)E;
    const size_t need_full = (size_t)(p - (char*)d_ws);

    const bool use_csr  = ws_size >= need_csr;
    const bool use_perm = ws_size >= need_perm;
    const bool use_ea   = ws_size >= need_full;

    const int tiles = (N + 63) / 64;

    gemm_enc<<<tiles, 512, 0, stream>>>(x, W_enc, b_enc, h, N);

    if (use_csr) {
        zero_cnt<<<(N + 255) / 256, 256, 0, stream>>>(cnt, N);
        hist_kernel<<<1024, 256, 0, stream>>>(ei, cnt, E);
        scan_kernel<<<1, 1024, 0, stream>>>(cnt, off, cur, N, E);
        scatter_kernel<<<1024, 256, 0, stream>>>(ei, cur, eids, E);
        if (use_perm)
            permute_kernel<<<4096, 256, 0, stream>>>(ei, eattr, eatten, eids,
                                                     srcp, attp, eap, E, use_ea ? 1 : 0);
    }

    for (int i = 0; i < L; ++i) {
        if (use_ea) {
            agg_gather<true><<<(N + 3) / 4, 256, 0, stream>>>(
                h, srcp, attp, eap, eids, eattr, off, W_ee, b_ee, zbuf, eps, i, N);
        } else if (use_perm) {
            agg_gather<false><<<(N + 3) / 4, 256, 0, stream>>>(
                h, srcp, attp, eap, eids, eattr, off, W_ee, b_ee, zbuf, eps, i, N);
        } else if (use_csr) {
            agg_kernel<<<(N + 3) / 4, 256, 0, stream>>>(
                h, ei, eattr, eatten, off, eids, W_ee, b_ee, zbuf, eps, i, N, E);
        } else {
            scale_init<<<2048, 256, 0, stream>>>(h, zbuf, eps, i, N * 128 / 4);
            edge_atomic<<<2048, 256, 0, stream>>>(h, ei, eattr, eatten, W_ee, b_ee, zbuf, E);
        }
        gemm_mlp<<<tiles, 512, 0, stream>>>(
            zbuf, W1 + (size_t)i * 128 * 128, b1 + i * 128,
            gam + i * 128, bet + i * 128, mu + i * 128, var + i * 128,
            W2 + (size_t)i * 128 * 128, b2 + i * 128,
            h, N);
    }
}